// Round 12
// baseline (18.609 us; speedup 1.0000x reference)
//
#include <hip/hip_runtime.h>
#include <hip/hip_fp16.h>

// SplatGaussian2D round 12: R11 structure (f16 LDS param packs + queue
// compaction) with the gaussian range SPLIT in 2 across blockIdx.y:
// 2048 blocks -> 8 blocks/CU, LDS 16.2KB, launch_bounds(256,8) -> 8 waves/SIMD
// (2x R11). Tests the latency-stall hypothesis at max occupancy.
// Out zeroed by memsetAsync; halves combine via rare global atomicAdd.

constexpr int   BN    = 8192;
constexpr int   NG    = 2048;
constexpr int   GS    = 2;               // gaussian splits
constexpr int   NGH   = NG / GS;         // 1024 per block
constexpr float SMIN  = 1.0f / 30.0f;
constexpr float SSPAN = (1.0f / 0.75f - 1.0f / 30.0f);
constexpr float MUSCALE = 1.05f * 256.0f;
constexpr float LOG2E = 1.44269504088896341f;
constexpr float QT    = 25.0f * 1.44269504088896341f;
constexpr float TWOPI = 6.283185307179586f;
constexpr int   BLOCK = 256;
constexpr int   RC    = 8;               // rays per block
constexpr int   GPT   = NGH / BLOCK;     // 4
constexpr int   QMAX  = 1024;

static __device__ __forceinline__ unsigned pk2h(float a, float b) {
    __half2 h = __floats2half2_rn(a, b);
    return __builtin_bit_cast(unsigned, h);
}
static __device__ __forceinline__ float2 unpk(unsigned u) {
    __half2 h = __builtin_bit_cast(__half2, u);
    return __half22float2(h);
}

__global__ __launch_bounds__(BLOCK, 8) void splat_one(
    const float* __restrict__ xb,   // [B,2]
    const float* __restrict__ xyz,  // [N,2]
    const float* __restrict__ feat, // [N,9,3]
    const float* __restrict__ opac, // [N]
    const float* __restrict__ scal, // [N,2]
    const float* __restrict__ rot,  // [N]
    float* __restrict__ out)        // [B,3] (pre-zeroed)
{
    __shared__ unsigned su0[NGH], su1[NGH], su2[NGH];  // {mx,my},{A,B},{C,-}
    __shared__ float    sray[RC * 2];
    __shared__ float    sacc[RC * 3];
    __shared__ unsigned queue[QMAX];
    __shared__ int      qcnt;

    const int tid = threadIdx.x;
    const int rc  = blockIdx.x;
    const int g0  = blockIdx.y * NGH;

    if (tid == 0) qcnt = 0;
    if (tid < RC) {
        const float2 t = reinterpret_cast<const float2*>(xb)[rc * RC + tid];
        sray[2 * tid + 0] = t.x - 256.0f;
        sray[2 * tid + 1] = t.y - 256.0f;
    }
    if (tid < RC * 3) sacc[tid] = 0.0f;

    // ---- prep: pack this half's gaussians into LDS (coalesced loads) ----
    #pragma unroll
    for (int k = 0; k < GPT; ++k) {
        const int gl = k * BLOCK + tid;
        const int g  = g0 + gl;
        const float2 xy = reinterpret_cast<const float2*>(xyz)[g];
        const float2 sc = reinterpret_cast<const float2*>(scal)[g];
        const float  rr = rot[g];
        const float mx = fminf(fmaxf(xy.x, -1.0f), 1.0f) * MUSCALE;
        const float my = fminf(fmaxf(xy.y, -1.0f), 1.0f) * MUSCALE;
        const float s0 = fminf(fmaxf(sc.x, 0.0f), 1.0f) * SSPAN + SMIN;
        const float s1 = fminf(fmaxf(sc.y, 0.0f), 1.0f) * SSPAN + SMIN;
        const float ang = (rr - floorf(rr)) * TWOPI;
        float sn, cs;
        __sincosf(ang, &sn, &cs);
        const float qsx = s0 * s0 * LOG2E;
        const float qsy = s1 * s1 * LOG2E;
        const float c2 = cs * cs, s2 = sn * sn;
        const float A  = fmaf(qsx, c2, qsy * s2);
        const float C  = fmaf(qsx, s2, qsy * c2);
        const float Bq = 2.0f * cs * sn * (qsy - qsx);
        su0[gl] = pk2h(mx, my);
        su1[gl] = pk2h(A, Bq);
        su2[gl] = pk2h(C, 0.0f);
    }
    __syncthreads();

    float rxs[RC], rys[RC];
    #pragma unroll
    for (int i = 0; i < RC; ++i) { rxs[i] = sray[2 * i]; rys[i] = sray[2 * i + 1]; }

    // ---- light phase: LDS-resident f16 test ----
    #pragma unroll
    for (int k = 0; k < GPT; ++k) {
        const int gl = k * BLOCK + tid;
        const float2 m  = unpk(su0[gl]);
        const float2 ab = unpk(su1[gl]);
        const float2 cc = unpk(su2[gl]);
        #pragma unroll
        for (int i = 0; i < RC; ++i) {
            const float vx = rxs[i] - m.x;
            const float vy = rys[i] - m.y;
            const float q  = fmaf(ab.x, vx * vx,
                             fmaf(ab.y, vx * vy, cc.x * (vy * vy)));
            if (q < QT) {
                const int idx = atomicAdd(&qcnt, 1);
                if (idx < QMAX) queue[idx] = ((unsigned)gl << 3) | (unsigned)i;
            }
        }
    }
    __syncthreads();

    // ---- heavy phase: exact recompute from raw f32 inputs ----
    const int n = min(qcnt, QMAX);
    for (int j = tid; j < n; j += BLOCK) {
        const unsigned e = queue[j];
        const int g = g0 + (int)(e >> 3);
        const int i = (int)(e & 7u);

        const float2 xy = reinterpret_cast<const float2*>(xyz)[g];
        const float2 sc = reinterpret_cast<const float2*>(scal)[g];
        const float  rr = rot[g];
        const float  op = fminf(fmaxf(opac[g], 0.0f), 1.0f);
        const float mx = fminf(fmaxf(xy.x, -1.0f), 1.0f) * MUSCALE;
        const float my = fminf(fmaxf(xy.y, -1.0f), 1.0f) * MUSCALE;
        const float s0 = fminf(fmaxf(sc.x, 0.0f), 1.0f) * SSPAN + SMIN;
        const float s1 = fminf(fmaxf(sc.y, 0.0f), 1.0f) * SSPAN + SMIN;
        const float ang = (rr - floorf(rr)) * TWOPI;
        const float cs = cosf(ang);
        const float sn = sinf(ang);

        const float vx = sray[2 * i + 0] - mx;
        const float vy = sray[2 * i + 1] - my;
        const float rx = fmaf(cs, vx, -sn * vy);
        const float ry = fmaf(sn, vx,  cs * vy);
        const float q  = fmaf(s0 * s0 * LOG2E, rx * rx,
                              (s1 * s1 * LOG2E) * (ry * ry));
        const float w  = exp2f(log2f(fmaxf(op, 1e-30f)) - q);

        const float iv  = rsqrtf(fmaxf(vx * vx + vy * vy, 1e-24f));
        const float s1v = rx * iv;
        const float c1v = ry * iv;
        const float s2v = 2.0f * s1v * c1v;
        const float c2v = fmaf(-2.0f * s1v, s1v, 1.0f);
        const float s3v = fmaf(s1v, c2v, c1v * s2v);
        const float c3v = fmaf(c1v, c2v, -s1v * s2v);
        const float s4v = 2.0f * s2v * c2v;
        const float c4v = fmaf(-2.0f * s2v, s2v, 1.0f);

        const float* __restrict__ fg = feat + (size_t)g * 27;
        float x0 = fg[0], x1 = fg[1], x2 = fg[2];
        x0 = fmaf(s1v, fg[3],  x0); x1 = fmaf(s1v, fg[4],  x1); x2 = fmaf(s1v, fg[5],  x2);
        x0 = fmaf(c1v, fg[6],  x0); x1 = fmaf(c1v, fg[7],  x1); x2 = fmaf(c1v, fg[8],  x2);
        x0 = fmaf(s2v, fg[9],  x0); x1 = fmaf(s2v, fg[10], x1); x2 = fmaf(s2v, fg[11], x2);
        x0 = fmaf(c2v, fg[12], x0); x1 = fmaf(c2v, fg[13], x1); x2 = fmaf(c2v, fg[14], x2);
        x0 = fmaf(s3v, fg[15], x0); x1 = fmaf(s3v, fg[16], x1); x2 = fmaf(s3v, fg[17], x2);
        x0 = fmaf(c3v, fg[18], x0); x1 = fmaf(c3v, fg[19], x1); x2 = fmaf(c3v, fg[20], x2);
        x0 = fmaf(s4v, fg[21], x0); x1 = fmaf(s4v, fg[22], x1); x2 = fmaf(s4v, fg[23], x2);
        x0 = fmaf(c4v, fg[24], x0); x1 = fmaf(c4v, fg[25], x1); x2 = fmaf(c4v, fg[26], x2);

        atomicAdd(&sacc[3 * i + 0], __fdividef(w, 1.0f + exp2f(-x0 * LOG2E)));
        atomicAdd(&sacc[3 * i + 1], __fdividef(w, 1.0f + exp2f(-x1 * LOG2E)));
        atomicAdd(&sacc[3 * i + 2], __fdividef(w, 1.0f + exp2f(-x2 * LOG2E)));
    }
    __syncthreads();

    // combine the GS halves via rare global atomics (out pre-zeroed)
    if (tid < RC * 3)
        atomicAdd(&out[rc * (RC * 3) + tid], sacc[tid]);
}

extern "C" void kernel_launch(void* const* d_in, const int* in_sizes, int n_in,
                              void* d_out, int out_size, void* d_ws, size_t ws_size,
                              hipStream_t stream) {
    const float* xb   = (const float*)d_in[0];
    const float* xyz  = (const float*)d_in[1];
    const float* feat = (const float*)d_in[2];
    const float* opac = (const float*)d_in[3];
    const float* scal = (const float*)d_in[4];
    const float* rot  = (const float*)d_in[5];
    float* out = (float*)d_out;

    hipMemsetAsync(out, 0, (size_t)out_size * sizeof(float), stream);
    splat_one<<<dim3(BN / RC, GS), dim3(BLOCK), 0, stream>>>(
        xb, xyz, feat, opac, scal, rot, out);
}

// Round 13
// 15.135 us; speedup vs baseline: 1.2295x; 1.2295x over previous
//
#include <hip/hip_runtime.h>

// SplatGaussian2D round 13: spatial tile binning, SINGLE dispatch.
// 8x8 tiles of 64px. Block = (tile, 1/8 ray-id range): scan rays -> LDS,
// scan gaussians w/ circle-vs-tile reject -> survivor ids, prep survivors
// one-per-lane (accurate trig), pair-test ~78x16, queue-compacted heavy,
// direct out writes (each ray in exactly one block). No ws, no memset.

constexpr int   BN    = 8192;
constexpr int   NG    = 2048;
constexpr float SMIN  = 1.0f / 30.0f;
constexpr float SSPAN = (1.0f / 0.75f - 1.0f / 30.0f);
constexpr float MUSCALE = 1.05f * 256.0f;
constexpr float LOG2E = 1.44269504088896341f;
constexpr float QT    = 25.0f * 1.44269504088896341f;
constexpr float TWOPI = 6.283185307179586f;
constexpr int   BLOCK = 256;
constexpr int   NT    = 64;              // 8x8 tiles
constexpr int   SUB   = 8;               // ray-id range splits
constexpr int   RPS   = BN / SUB;        // 1024 rays scanned per block
constexpr int   CAPG  = 384;             // gaussians per tile (mean ~78)
constexpr int   CAPR  = 64;              // rays per (tile,sub) (mean ~16)
constexpr int   QCAP  = 768;             // valid pairs per block (mean ~76)

__global__ __launch_bounds__(BLOCK) void splat_tiled(
    const float* __restrict__ xb,   // [B,2]
    const float* __restrict__ xyz,  // [N,2]
    const float* __restrict__ feat, // [N,9,3]
    const float* __restrict__ opac, // [N]
    const float* __restrict__ scal, // [N,2]
    const float* __restrict__ rot,  // [N]
    float* __restrict__ out)        // [B,3]
{
    __shared__ int      sgid[CAPG];
    __shared__ float    gmx[CAPG], gmy[CAPG], gcs[CAPG], gsn[CAPG];
    __shared__ float    gqx[CAPG], gqy[CAPG], gl2[CAPG];
    __shared__ float    rpx[CAPR], rpy[CAPR];
    __shared__ int      srid[CAPR];
    __shared__ float    sacc[CAPR * 3];
    __shared__ unsigned queue[QCAP];
    __shared__ int      gcnt, rcnt, qcnt;

    const int tid  = threadIdx.x;
    const int tile = blockIdx.x;
    const int sub  = blockIdx.y;
    const int txi  = tile & 7;
    const int tyi  = tile >> 3;
    const float tcx = txi * 64.0f + 32.0f - 256.0f;   // tile center, centered coords
    const float tcy = tyi * 64.0f + 32.0f - 256.0f;

    if (tid == 0) { gcnt = 0; rcnt = 0; qcnt = 0; }
    for (int t = tid; t < CAPR * 3; t += BLOCK) sacc[t] = 0.0f;
    __syncthreads();

    // ---- ray scan: this block's 1024-ray id range, keep in-tile ----
    #pragma unroll
    for (int k = 0; k < RPS / BLOCK; ++k) {
        const int r = sub * RPS + k * BLOCK + tid;
        const float2 p = reinterpret_cast<const float2*>(xb)[r];
        const int rtx = (int)(p.x * (1.0f / 64.0f));
        const int rty = (int)(p.y * (1.0f / 64.0f));
        if (rtx == txi && rty == tyi) {
            const int i = atomicAdd(&rcnt, 1);
            if (i < CAPR) { rpx[i] = p.x - 256.0f; rpy[i] = p.y - 256.0f; srid[i] = r; }
        }
    }

    // ---- gaussian scan: circle-vs-tile conservative reject ----
    #pragma unroll
    for (int k = 0; k < NG / BLOCK; ++k) {
        const int g = k * BLOCK + tid;
        const float2 xy = reinterpret_cast<const float2*>(xyz)[g];
        const float2 sc = reinterpret_cast<const float2*>(scal)[g];
        const float mx = fminf(fmaxf(xy.x, -1.0f), 1.0f) * MUSCALE;
        const float my = fminf(fmaxf(xy.y, -1.0f), 1.0f) * MUSCALE;
        const float s0 = fminf(fmaxf(sc.x, 0.0f), 1.0f) * SSPAN + SMIN;
        const float s1 = fminf(fmaxf(sc.y, 0.0f), 1.0f) * SSPAN + SMIN;
        const float rmax = 5.05f / fminf(s0, s1);     // conservative reach
        const float dx = fmaxf(fabsf(mx - tcx) - 32.0f, 0.0f);
        const float dy = fmaxf(fabsf(my - tcy) - 32.0f, 0.0f);
        if (fmaf(dx, dx, dy * dy) <= rmax * rmax) {
            const int i = atomicAdd(&gcnt, 1);
            if (i < CAPG) sgid[i] = g;
        }
    }
    __syncthreads();

    const int ng = min(gcnt, CAPG);
    const int nr = min(rcnt, CAPR);

    // ---- prep survivors, one per lane (accurate trig) ----
    for (int j = tid; j < ng; j += BLOCK) {
        const int g = sgid[j];
        const float2 xy = reinterpret_cast<const float2*>(xyz)[g];
        const float2 sc = reinterpret_cast<const float2*>(scal)[g];
        const float  rr = rot[g];
        const float  op = fminf(fmaxf(opac[g], 0.0f), 1.0f);
        const float s0 = fminf(fmaxf(sc.x, 0.0f), 1.0f) * SSPAN + SMIN;
        const float s1 = fminf(fmaxf(sc.y, 0.0f), 1.0f) * SSPAN + SMIN;
        const float ang = (rr - floorf(rr)) * TWOPI;
        gmx[j] = fminf(fmaxf(xy.x, -1.0f), 1.0f) * MUSCALE;
        gmy[j] = fminf(fmaxf(xy.y, -1.0f), 1.0f) * MUSCALE;
        gcs[j] = cosf(ang);
        gsn[j] = sinf(ang);
        gqx[j] = s0 * s0 * LOG2E;
        gqy[j] = s1 * s1 * LOG2E;
        gl2[j] = log2f(fmaxf(op, 1e-30f));
    }
    __syncthreads();

    // ---- pair test: rays padded to 64 lanes, queue valid pairs ----
    const int npair = ng << 6;
    for (int p = tid; p < npair; p += BLOCK) {
        const int gl = p >> 6;
        const int rl = p & 63;
        if (rl < nr) {
            const float vx = rpx[rl] - gmx[gl];
            const float vy = rpy[rl] - gmy[gl];
            const float rx = fmaf(gcs[gl], vx, -gsn[gl] * vy);
            const float ry = fmaf(gsn[gl], vx,  gcs[gl] * vy);
            const float q  = fmaf(gqx[gl], rx * rx, gqy[gl] * (ry * ry));
            if (q < QT) {
                const int i = atomicAdd(&qcnt, 1);
                if (i < QCAP) queue[i] = (unsigned)((gl << 8) | rl);
            }
        }
    }
    __syncthreads();

    // ---- heavy phase: one valid pair per lane ----
    const int nq = min(qcnt, QCAP);
    for (int j = tid; j < nq; j += BLOCK) {
        const unsigned e = queue[j];
        const int gl = (int)(e >> 8);
        const int rl = (int)(e & 255u);

        const float vx = rpx[rl] - gmx[gl];
        const float vy = rpy[rl] - gmy[gl];
        const float cs = gcs[gl], sn = gsn[gl];
        const float rx = fmaf(cs, vx, -sn * vy);
        const float ry = fmaf(sn, vx,  cs * vy);
        const float q  = fmaf(gqx[gl], rx * rx, gqy[gl] * (ry * ry));
        const float w  = exp2f(gl2[gl] - q);

        const float iv  = rsqrtf(fmaxf(vx * vx + vy * vy, 1e-24f));
        const float s1v = rx * iv;
        const float c1v = ry * iv;
        const float s2v = 2.0f * s1v * c1v;
        const float c2v = fmaf(-2.0f * s1v, s1v, 1.0f);
        const float s3v = fmaf(s1v, c2v, c1v * s2v);
        const float c3v = fmaf(c1v, c2v, -s1v * s2v);
        const float s4v = 2.0f * s2v * c2v;
        const float c4v = fmaf(-2.0f * s2v, s2v, 1.0f);

        const float* __restrict__ fg = feat + (size_t)sgid[gl] * 27;
        float x0 = fg[0], x1 = fg[1], x2 = fg[2];
        x0 = fmaf(s1v, fg[3],  x0); x1 = fmaf(s1v, fg[4],  x1); x2 = fmaf(s1v, fg[5],  x2);
        x0 = fmaf(c1v, fg[6],  x0); x1 = fmaf(c1v, fg[7],  x1); x2 = fmaf(c1v, fg[8],  x2);
        x0 = fmaf(s2v, fg[9],  x0); x1 = fmaf(s2v, fg[10], x1); x2 = fmaf(s2v, fg[11], x2);
        x0 = fmaf(c2v, fg[12], x0); x1 = fmaf(c2v, fg[13], x1); x2 = fmaf(c2v, fg[14], x2);
        x0 = fmaf(s3v, fg[15], x0); x1 = fmaf(s3v, fg[16], x1); x2 = fmaf(s3v, fg[17], x2);
        x0 = fmaf(c3v, fg[18], x0); x1 = fmaf(c3v, fg[19], x1); x2 = fmaf(c3v, fg[20], x2);
        x0 = fmaf(s4v, fg[21], x0); x1 = fmaf(s4v, fg[22], x1); x2 = fmaf(s4v, fg[23], x2);
        x0 = fmaf(c4v, fg[24], x0); x1 = fmaf(c4v, fg[25], x1); x2 = fmaf(c4v, fg[26], x2);

        atomicAdd(&sacc[3 * rl + 0], __fdividef(w, 1.0f + exp2f(-x0 * LOG2E)));
        atomicAdd(&sacc[3 * rl + 1], __fdividef(w, 1.0f + exp2f(-x1 * LOG2E)));
        atomicAdd(&sacc[3 * rl + 2], __fdividef(w, 1.0f + exp2f(-x2 * LOG2E)));
    }
    __syncthreads();

    // ---- write this block's rays (exact partition -> plain stores) ----
    for (int t = tid; t < nr; t += BLOCK) {
        const int r = srid[t];
        out[3 * r + 0] = sacc[3 * t + 0];
        out[3 * r + 1] = sacc[3 * t + 1];
        out[3 * r + 2] = sacc[3 * t + 2];
    }
}

extern "C" void kernel_launch(void* const* d_in, const int* in_sizes, int n_in,
                              void* d_out, int out_size, void* d_ws, size_t ws_size,
                              hipStream_t stream) {
    const float* xb   = (const float*)d_in[0];
    const float* xyz  = (const float*)d_in[1];
    const float* feat = (const float*)d_in[2];
    const float* opac = (const float*)d_in[3];
    const float* scal = (const float*)d_in[4];
    const float* rot  = (const float*)d_in[5];
    float* out = (float*)d_out;

    splat_tiled<<<dim3(NT, SUB), dim3(BLOCK), 0, stream>>>(
        xb, xyz, feat, opac, scal, rot, out);
}